// Round 1
// baseline (952.817 us; speedup 1.0000x reference)
//
#include <hip/hip_runtime.h>
#include <math.h>

#define N_NODES 100000
#define N_EDGES 1600000
#define D 64
#define LN_EPS 1e-5f

// ---------------- zero scratch ----------------
__global__ void k_zero(float* __restrict__ denom, float* __restrict__ aggr) {
    int stride = gridDim.x * blockDim.x;
    int tid = blockIdx.x * blockDim.x + threadIdx.x;
    for (int i = tid; i < N_NODES; i += stride) denom[i] = 0.f;
    for (int i = tid; i < N_NODES * D; i += stride) aggr[i] = 0.f;
}

// ---------------- per-edge denom scatter ----------------
__global__ void k_denom(const int* __restrict__ dst, const float* __restrict__ adv,
                        float* __restrict__ denom) {
    int stride = gridDim.x * blockDim.x;
    for (int e = blockIdx.x * blockDim.x + threadIdx.x; e < N_EDGES; e += stride)
        atomicAdd(&denom[dst[e]], adv[e]);
}

// ---------------- per-edge message + scatter-add (one wave per edge) ----------------
__global__ void k_aggr(const int* __restrict__ src, const int* __restrict__ dst,
                       const float* __restrict__ adv, const float* __restrict__ denom,
                       const float* __restrict__ x, float* __restrict__ aggr) {
    const int lane = threadIdx.x & 63;
    int wid = (blockIdx.x * blockDim.x + threadIdx.x) >> 6;
    const int nwaves = (gridDim.x * blockDim.x) >> 6;
    for (int e = wid; e < N_EDGES; e += nwaves) {
        int s = src[e];
        int d = dst[e];
        float att = adv[e] / denom[d];
        float v = x[(long)s * D + lane] * att;
        atomicAdd(&aggr[(long)d * D + lane], v);
    }
}

// ---------------- per-node update: gelu+res, 64x64 matvec, LayerNorm ----------------
__global__ __launch_bounds__(256) void k_update(const float* __restrict__ aggr,
                                                const float* __restrict__ x,
                                                const float* __restrict__ W,
                                                const float* __restrict__ b,
                                                const float* __restrict__ g,
                                                const float* __restrict__ be,
                                                float* __restrict__ out) {
    const int lane = threadIdx.x & 63;
    const int wid = threadIdx.x >> 6;  // 0..3 (wave per node)
    __shared__ float hs[4][D];
    for (int base = blockIdx.x * 4; base < N_NODES; base += gridDim.x * 4) {
        const int node = base + wid;
        float h = 0.f;
        if (node < N_NODES) {
            float a = aggr[(long)node * D + lane];
            float xv = x[(long)node * D + lane];
            // exact GELU: 0.5*a*(1+erf(a/sqrt(2)))
            float ge = 0.5f * a * (1.f + erff(a * 0.70710678118654752f));
            h = ge + xv;
        }
        hs[wid][lane] = h;
        __syncthreads();
        float acc = b[lane];
#pragma unroll 8
        for (int k = 0; k < D; ++k)
            acc = fmaf(hs[wid][k], W[k * D + lane], acc);
        __syncthreads();
        if (node < N_NODES) {
            // LayerNorm across the 64 lanes
            float s = acc;
            for (int m = 32; m; m >>= 1) s += __shfl_xor(s, m, 64);
            float mu = s * (1.f / 64.f);
            float dv = acc - mu;
            float v2 = dv * dv;
            for (int m = 32; m; m >>= 1) v2 += __shfl_xor(v2, m, 64);
            float var = v2 * (1.f / 64.f);
            out[(long)node * D + lane] = dv * rsqrtf(var + LN_EPS) * g[lane] + be[lane];
        }
    }
}

static void run_layer(const float* x, const int* src, const int* dst, const float* adv,
                      const float* W, const float* b, const float* g, const float* be,
                      float* out, float* denom, float* aggr, hipStream_t stream) {
    k_zero<<<2048, 256, 0, stream>>>(denom, aggr);
    k_denom<<<2048, 256, 0, stream>>>(dst, adv, denom);
    k_aggr<<<2048, 256, 0, stream>>>(src, dst, adv, denom, x, aggr);
    k_update<<<4096, 256, 0, stream>>>(aggr, x, W, b, g, be, out);
}

extern "C" void kernel_launch(void* const* d_in, const int* in_sizes, int n_in,
                              void* d_out, int out_size, void* d_ws, size_t ws_size,
                              hipStream_t stream) {
    const float* node_attr = (const float*)d_in[0];
    const int* edge_index = (const int*)d_in[1];
    // d_in[2] = batch_idx (unused)
    const float* adv0 = (const float*)d_in[3];
    const float* adv1 = (const float*)d_in[4];
    const float* W0 = (const float*)d_in[5];
    const float* b0 = (const float*)d_in[6];
    const float* g0 = (const float*)d_in[7];
    const float* be0 = (const float*)d_in[8];
    const float* W1 = (const float*)d_in[9];
    const float* b1 = (const float*)d_in[10];
    const float* g1 = (const float*)d_in[11];
    const float* be1 = (const float*)d_in[12];

    const int* src = edge_index;            // edge_index[0]
    const int* dst = edge_index + N_EDGES;  // edge_index[1]

    float* denom = (float*)d_ws;            // [N]
    float* aggr = denom + N_NODES;          // [N*D]
    float* out = (float*)d_out;             // [N*D]; also holds h1 between layers

    // layer 1: x = node_attr -> out (h1)
    run_layer(node_attr, src, dst, adv0, W0, b0, g0, be0, out, denom, aggr, stream);
    // layer 2: x = h1 (in d_out) -> out (in-place safe: update is per-node elementwise)
    run_layer(out, src, dst, adv1, W1, b1, g1, be1, out, denom, aggr, stream);
}

// Round 2
// 487.510 us; speedup vs baseline: 1.9545x; 1.9545x over previous
//
#include <hip/hip_runtime.h>
#include <math.h>

#define N_NODES 100000
#define N_EDGES 1600000
#define D 64
#define LN_EPS 1e-5f
#define SCAN_NB 391  // ceil(100000/256)

// ---------------- zero the per-node counters ----------------
__global__ void k_zero_counts(int* __restrict__ counts) {
    int i = blockIdx.x * 256 + threadIdx.x;
    if (i < N_NODES) counts[i] = 0;
}

// ---------------- histogram of dst ----------------
__global__ void k_hist(const int* __restrict__ dst, int* __restrict__ counts) {
    int e = blockIdx.x * 256 + threadIdx.x;  // exact: 6250*256 == N_EDGES
    atomicAdd(&counts[dst[e]], 1);
}

// ---------------- scan step 1: per-block exclusive scan + block sums ----------------
__global__ void k_scan1(const int* __restrict__ counts, int* __restrict__ offsets,
                        int* __restrict__ blockSums) {
    __shared__ int s[256];
    int tid = threadIdx.x;
    int i = blockIdx.x * 256 + tid;
    int v = (i < N_NODES) ? counts[i] : 0;
    s[tid] = v;
    __syncthreads();
    for (int off = 1; off < 256; off <<= 1) {
        int t = (tid >= off) ? s[tid - off] : 0;
        __syncthreads();
        s[tid] += t;
        __syncthreads();
    }
    if (i < N_NODES) offsets[i] = s[tid] - v;  // exclusive within block
    if (tid == 255) blockSums[blockIdx.x] = s[255];
}

// ---------------- scan step 2: exclusive scan of block sums (single block) ----------------
__global__ void k_scan2(int* __restrict__ blockSums) {
    __shared__ int s[512];
    int tid = threadIdx.x;
    int v = (tid < SCAN_NB) ? blockSums[tid] : 0;
    s[tid] = v;
    __syncthreads();
    for (int off = 1; off < 512; off <<= 1) {
        int t = (tid >= off) ? s[tid - off] : 0;
        __syncthreads();
        s[tid] += t;
        __syncthreads();
    }
    if (tid < SCAN_NB) blockSums[tid] = s[tid] - v;  // exclusive
}

// ---------------- scan step 3: add block offsets; init cursor ----------------
__global__ void k_scan3(int* __restrict__ offsets, const int* __restrict__ blockSums,
                        int* __restrict__ cursor) {
    int i = blockIdx.x * 256 + threadIdx.x;
    if (i < N_NODES) {
        int o = offsets[i] + blockSums[blockIdx.x];
        offsets[i] = o;
        cursor[i] = o;
    }
    if (i == 0) offsets[N_NODES] = N_EDGES;
}

// ---------------- bucket edges into CSR order: record = {src, adv0, adv1, 0} ----------------
__global__ void k_bucket(const int* __restrict__ src, const int* __restrict__ dst,
                         const float* __restrict__ adv0, const float* __restrict__ adv1,
                         int* __restrict__ cursor, int4* __restrict__ edges) {
    int e = blockIdx.x * 256 + threadIdx.x;  // exact
    int d = dst[e];
    int pos = atomicAdd(&cursor[d], 1);
    int4 rec;
    rec.x = src[e];
    rec.y = __float_as_int(adv0[e]);
    rec.z = __float_as_int(adv1[e]);
    rec.w = 0;
    edges[pos] = rec;
}

// ---------------- fused layer: gather-aggregate + gelu/res + matvec + LN ----------------
template <int SEL>
__global__ __launch_bounds__(256) void k_layer(const float* __restrict__ x,
                                               const int4* __restrict__ edges,
                                               const int* __restrict__ offsets,
                                               const float* __restrict__ W,
                                               const float* __restrict__ b,
                                               const float* __restrict__ g,
                                               const float* __restrict__ be,
                                               float* __restrict__ out) {
    const int lane = threadIdx.x & 63;
    const int wid = threadIdx.x >> 6;            // 4 waves/block, one node each
    const int node = blockIdx.x * 4 + wid;       // 25000*4 == N_NODES exactly
    const int beg = offsets[node];
    const int end = offsets[node + 1];

    float acc = 0.f, sadv = 0.f;
    int i = beg;
    if (i < end) {
        int4 rec = edges[i];
        for (;;) {
            int4 cur = rec;
            ++i;
            if (i < end) rec = edges[i];  // prefetch next record
            float a = __int_as_float(SEL ? cur.z : cur.y);
            acc = fmaf(x[(size_t)cur.x * D + lane], a, acc);
            sadv += a;
            if (i >= end) break;
        }
    }
    float aggr = (end > beg) ? acc / sadv : 0.f;

    float xv = x[(size_t)node * D + lane];
    // exact GELU: 0.5*a*(1+erf(a/sqrt(2)))
    float h = 0.5f * aggr * (1.f + erff(aggr * 0.70710678118654752f)) + xv;

    __shared__ float hs[4][D];
    hs[wid][lane] = h;
    __syncthreads();

    float acc2 = b[lane];
#pragma unroll 16
    for (int k = 0; k < D; ++k)
        acc2 = fmaf(hs[wid][k], W[k * D + lane], acc2);

    // LayerNorm across the 64 lanes
    float s = acc2;
    for (int m = 32; m; m >>= 1) s += __shfl_xor(s, m, 64);
    float mu = s * (1.f / 64.f);
    float dv = acc2 - mu;
    float v2 = dv * dv;
    for (int m = 32; m; m >>= 1) v2 += __shfl_xor(v2, m, 64);
    float var = v2 * (1.f / 64.f);
    out[(size_t)node * D + lane] = dv * rsqrtf(var + LN_EPS) * g[lane] + be[lane];
}

extern "C" void kernel_launch(void* const* d_in, const int* in_sizes, int n_in,
                              void* d_out, int out_size, void* d_ws, size_t ws_size,
                              hipStream_t stream) {
    const float* node_attr = (const float*)d_in[0];
    const int* edge_index = (const int*)d_in[1];
    // d_in[2] = batch_idx (unused)
    const float* adv0 = (const float*)d_in[3];
    const float* adv1 = (const float*)d_in[4];
    const float* W0 = (const float*)d_in[5];
    const float* b0 = (const float*)d_in[6];
    const float* g0 = (const float*)d_in[7];
    const float* be0 = (const float*)d_in[8];
    const float* W1 = (const float*)d_in[9];
    const float* b1 = (const float*)d_in[10];
    const float* g1 = (const float*)d_in[11];
    const float* be1 = (const float*)d_in[12];

    const int* src = edge_index;            // edge_index[0]
    const int* dst = edge_index + N_EDGES;  // edge_index[1]

    // workspace layout (~52.4 MB)
    int4* edges = (int4*)d_ws;                       // [E] 25.6 MB (16B-aligned at base)
    float* h1 = (float*)(edges + N_EDGES);           // [N*D] 25.6 MB
    int* offsets = (int*)(h1 + (size_t)N_NODES * D); // [N+1]
    int* cursor = offsets + (N_NODES + 1);           // [N]
    int* counts = cursor + N_NODES;                  // [N]
    int* blockSums = counts + N_NODES;               // [512]

    float* out = (float*)d_out;

    // ---- build CSR by dst (once; serves both layers) ----
    k_zero_counts<<<SCAN_NB, 256, 0, stream>>>(counts);
    k_hist<<<N_EDGES / 256, 256, 0, stream>>>(dst, counts);
    k_scan1<<<SCAN_NB, 256, 0, stream>>>(counts, offsets, blockSums);
    k_scan2<<<1, 512, 0, stream>>>(blockSums);
    k_scan3<<<SCAN_NB, 256, 0, stream>>>(offsets, blockSums, cursor);
    k_bucket<<<N_EDGES / 256, 256, 0, stream>>>(src, dst, adv0, adv1, cursor, edges);

    // ---- layer 1: node_attr -> h1 ----
    k_layer<0><<<N_NODES / 4, 256, 0, stream>>>(node_attr, edges, offsets, W0, b0, g0, be0, h1);
    // ---- layer 2: h1 -> out ----
    k_layer<1><<<N_NODES / 4, 256, 0, stream>>>(h1, edges, offsets, W1, b1, g1, be1, out);
}

// Round 3
// 356.495 us; speedup vs baseline: 2.6727x; 1.3675x over previous
//
#include <hip/hip_runtime.h>
#include <math.h>

#define N_NODES 100000
#define N_EDGES 1600000
#define D 64
#define LN_EPS 1e-5f
#define SCAN_NB 391   // ceil(100000/256)
#define NQ (N_EDGES / 4)  // 400000 quads

// ---------------- zero the per-node counters ----------------
__global__ void k_zero_counts(int* __restrict__ counts) {
    int i = blockIdx.x * 256 + threadIdx.x;
    if (i < N_NODES) counts[i] = 0;
}

// ---------------- histogram of dst (4 edges/thread) ----------------
__global__ void k_hist(const int4* __restrict__ dst4, int* __restrict__ counts) {
    int q = blockIdx.x * 256 + threadIdx.x;
    if (q < NQ) {
        int4 d = dst4[q];
        atomicAdd(&counts[d.x], 1);
        atomicAdd(&counts[d.y], 1);
        atomicAdd(&counts[d.z], 1);
        atomicAdd(&counts[d.w], 1);
    }
}

// ---------------- scan step 1: per-block exclusive scan + block sums ----------------
__global__ void k_scan1(const int* __restrict__ counts, int* __restrict__ offsets,
                        int* __restrict__ blockSums) {
    __shared__ int s[256];
    int tid = threadIdx.x;
    int i = blockIdx.x * 256 + tid;
    int v = (i < N_NODES) ? counts[i] : 0;
    s[tid] = v;
    __syncthreads();
    for (int off = 1; off < 256; off <<= 1) {
        int t = (tid >= off) ? s[tid - off] : 0;
        __syncthreads();
        s[tid] += t;
        __syncthreads();
    }
    if (i < N_NODES) offsets[i] = s[tid] - v;  // exclusive within block
    if (tid == 255) blockSums[blockIdx.x] = s[255];
}

// ---------------- scan step 2: exclusive scan of block sums (single block) ----------------
__global__ void k_scan2(int* __restrict__ blockSums) {
    __shared__ int s[512];
    int tid = threadIdx.x;
    int v = (tid < SCAN_NB) ? blockSums[tid] : 0;
    s[tid] = v;
    __syncthreads();
    for (int off = 1; off < 512; off <<= 1) {
        int t = (tid >= off) ? s[tid - off] : 0;
        __syncthreads();
        s[tid] += t;
        __syncthreads();
    }
    if (tid < SCAN_NB) blockSums[tid] = s[tid] - v;  // exclusive
}

// ---------------- scan step 3: add block offsets; init cursor ----------------
__global__ void k_scan3(int* __restrict__ offsets, const int* __restrict__ blockSums,
                        int* __restrict__ cursor) {
    int i = blockIdx.x * 256 + threadIdx.x;
    if (i < N_NODES) {
        int o = offsets[i] + blockSums[blockIdx.x];
        offsets[i] = o;
        cursor[i] = o;
    }
    if (i == 0) offsets[N_NODES] = N_EDGES;
}

// ---------------- bucket edges into CSR order, SoA (4 edges/thread) ----------------
__global__ void k_bucket(const int4* __restrict__ src4, const int4* __restrict__ dst4,
                         const float4* __restrict__ adv04, const float4* __restrict__ adv14,
                         int* __restrict__ cursor, int* __restrict__ srcCSR,
                         float* __restrict__ a0CSR, float* __restrict__ a1CSR) {
    int q = blockIdx.x * 256 + threadIdx.x;
    if (q >= NQ) return;
    int4 s = src4[q];
    int4 d = dst4[q];
    float4 a0 = adv04[q];
    float4 a1 = adv14[q];
    int p;
    p = atomicAdd(&cursor[d.x], 1); srcCSR[p] = s.x; a0CSR[p] = a0.x; a1CSR[p] = a1.x;
    p = atomicAdd(&cursor[d.y], 1); srcCSR[p] = s.y; a0CSR[p] = a0.y; a1CSR[p] = a1.y;
    p = atomicAdd(&cursor[d.z], 1); srcCSR[p] = s.z; a0CSR[p] = a0.z; a1CSR[p] = a1.z;
    p = atomicAdd(&cursor[d.w], 1); srcCSR[p] = s.w; a0CSR[p] = a0.w; a1CSR[p] = a1.w;
}

// ---------------- fused layer: gather-aggregate + gelu/res + matvec + LN ----------------
__global__ __launch_bounds__(256) void k_layer(const float* __restrict__ x,
                                               const int* __restrict__ srcCSR,
                                               const float* __restrict__ advCSR,
                                               const int* __restrict__ offsets,
                                               const float* __restrict__ W,
                                               const float* __restrict__ b,
                                               const float* __restrict__ g,
                                               const float* __restrict__ be,
                                               float* __restrict__ out) {
    const int lane = threadIdx.x & 63;
    const int wid = threadIdx.x >> 6;       // 4 waves/block, one node each
    const int node = blockIdx.x * 4 + wid;  // 25000*4 == N_NODES exactly
    const int beg = offsets[node];
    const int end = offsets[node + 1];

    float acc0 = 0.f, acc1 = 0.f;
    float sadv = 0.f;
    for (int base = beg; base < end; base += 64) {
        const int n = min(64, end - base);
        int sv = 0;
        float av = 0.f;
        if (lane < n) {
            sv = srcCSR[base + lane];
            av = advCSR[base + lane];
        }
        sadv += av;  // masked lanes contribute 0
        const int avi = __float_as_int(av);
        int k = 0;
        for (; k + 4 <= n; k += 4) {
            int s0 = __builtin_amdgcn_readlane(sv, k);
            int s1 = __builtin_amdgcn_readlane(sv, k + 1);
            int s2 = __builtin_amdgcn_readlane(sv, k + 2);
            int s3 = __builtin_amdgcn_readlane(sv, k + 3);
            float a0 = __int_as_float(__builtin_amdgcn_readlane(avi, k));
            float a1 = __int_as_float(__builtin_amdgcn_readlane(avi, k + 1));
            float a2 = __int_as_float(__builtin_amdgcn_readlane(avi, k + 2));
            float a3 = __int_as_float(__builtin_amdgcn_readlane(avi, k + 3));
            float x0 = x[(unsigned)(s0 * D) + lane];
            float x1 = x[(unsigned)(s1 * D) + lane];
            float x2 = x[(unsigned)(s2 * D) + lane];
            float x3 = x[(unsigned)(s3 * D) + lane];
            acc0 = fmaf(x0, a0, acc0);
            acc1 = fmaf(x1, a1, acc1);
            acc0 = fmaf(x2, a2, acc0);
            acc1 = fmaf(x3, a3, acc1);
        }
        for (; k < n; ++k) {
            int s0 = __builtin_amdgcn_readlane(sv, k);
            float a0 = __int_as_float(__builtin_amdgcn_readlane(avi, k));
            acc0 = fmaf(x[(unsigned)(s0 * D) + lane], a0, acc0);
        }
    }
    // wave-reduce sadv (the softmax denominator for this node)
    for (int m = 32; m; m >>= 1) sadv += __shfl_xor(sadv, m, 64);
    float acc = acc0 + acc1;
    float aggr = (end > beg) ? acc / sadv : 0.f;

    float xv = x[(unsigned)(node * D) + lane];
    // exact GELU: 0.5*a*(1+erf(a/sqrt(2)))
    float h = 0.5f * aggr * (1.f + erff(aggr * 0.70710678118654752f)) + xv;

    __shared__ float hs[4][D];
    hs[wid][lane] = h;
    __syncthreads();

    float acc2 = b[lane];
#pragma unroll 16
    for (int k = 0; k < D; ++k)
        acc2 = fmaf(hs[wid][k], W[k * D + lane], acc2);

    // LayerNorm across the 64 lanes
    float s = acc2;
    for (int m = 32; m; m >>= 1) s += __shfl_xor(s, m, 64);
    float mu = s * (1.f / 64.f);
    float dv = acc2 - mu;
    float v2 = dv * dv;
    for (int m = 32; m; m >>= 1) v2 += __shfl_xor(v2, m, 64);
    float var = v2 * (1.f / 64.f);
    out[(unsigned)(node * D) + lane] = dv * rsqrtf(var + LN_EPS) * g[lane] + be[lane];
}

extern "C" void kernel_launch(void* const* d_in, const int* in_sizes, int n_in,
                              void* d_out, int out_size, void* d_ws, size_t ws_size,
                              hipStream_t stream) {
    const float* node_attr = (const float*)d_in[0];
    const int* edge_index = (const int*)d_in[1];
    // d_in[2] = batch_idx (unused)
    const float* adv0 = (const float*)d_in[3];
    const float* adv1 = (const float*)d_in[4];
    const float* W0 = (const float*)d_in[5];
    const float* b0 = (const float*)d_in[6];
    const float* g0 = (const float*)d_in[7];
    const float* be0 = (const float*)d_in[8];
    const float* W1 = (const float*)d_in[9];
    const float* b1 = (const float*)d_in[10];
    const float* g1 = (const float*)d_in[11];
    const float* be1 = (const float*)d_in[12];

    const int4* src4 = (const int4*)edge_index;               // edge_index[0]
    const int4* dst4 = (const int4*)(edge_index + N_EDGES);   // edge_index[1]
    const float4* adv04 = (const float4*)adv0;
    const float4* adv14 = (const float4*)adv1;

    // workspace layout (~52.4 MB)
    int* srcCSR = (int*)d_ws;                        // [E] 6.4 MB
    float* a0CSR = (float*)(srcCSR + N_EDGES);       // [E] 6.4 MB
    float* a1CSR = a0CSR + N_EDGES;                  // [E] 6.4 MB
    float* h1 = a1CSR + N_EDGES;                     // [N*D] 25.6 MB
    int* offsets = (int*)(h1 + (size_t)N_NODES * D); // [N+1]
    int* cursor = offsets + (N_NODES + 1);           // [N]
    int* counts = cursor + N_NODES;                  // [N]
    int* blockSums = counts + N_NODES;               // [512]

    float* out = (float*)d_out;

    // ---- build CSR by dst (once; serves both layers) ----
    k_zero_counts<<<SCAN_NB, 256, 0, stream>>>(counts);
    k_hist<<<(NQ + 255) / 256, 256, 0, stream>>>(dst4, counts);
    k_scan1<<<SCAN_NB, 256, 0, stream>>>(counts, offsets, blockSums);
    k_scan2<<<1, 512, 0, stream>>>(blockSums);
    k_scan3<<<SCAN_NB, 256, 0, stream>>>(offsets, blockSums, cursor);
    k_bucket<<<(NQ + 255) / 256, 256, 0, stream>>>(src4, dst4, adv04, adv14, cursor,
                                                   srcCSR, a0CSR, a1CSR);

    // ---- layer 1: node_attr -> h1 ----
    k_layer<<<N_NODES / 4, 256, 0, stream>>>(node_attr, srcCSR, a0CSR, offsets,
                                             W0, b0, g0, be0, h1);
    // ---- layer 2: h1 -> out ----
    k_layer<<<N_NODES / 4, 256, 0, stream>>>(h1, srcCSR, a1CSR, offsets,
                                             W1, b1, g1, be1, out);
}